// Round 22
// baseline (193.926 us; speedup 1.0000x reference)
//
#include <hip/hip_runtime.h>
#include <hip/hip_bf16.h>

typedef unsigned short u16;
typedef unsigned int   u32;

using bf8 = __attribute__((ext_vector_type(8))) __bf16;
using f4  = __attribute__((ext_vector_type(4))) float;

__device__ __forceinline__ float b2f(u16 u) {
    union { u32 i; float f; } v; v.i = ((u32)u) << 16; return v.f;
}
__device__ __forceinline__ u16 f2b(float f) {
    union { float f; u32 i; } v; v.f = f;
    u32 x = v.i;
    x += 0x7fffu + ((x >> 16) & 1u);   // RNE
    return (u16)(x >> 16);
}
// Packed fp32x2 -> bf16x2 (low = first arg).
__device__ __forceinline__ u32 pk2(float lo, float hi) {
    union { __hip_bfloat162 h; u32 u; } v;
    v.h = __float22bfloat162_rn(make_float2(lo, hi));
    return v.u;
}

// ---------------------------------------------------------------------------
// Weight swizzle (verified layout — unchanged; frags used as A-operands):
// dst[((kt*16+ct)*64+lane)*8+j] = bf16(W[kt*32+(lane>>4)*8+j][ct*16+(lane&15)])
// ---------------------------------------------------------------------------
__global__ void swz_all(const float* __restrict__ w1, const float* __restrict__ w3,
                        const float* __restrict__ w2, const float* __restrict__ w4,
                        const float* __restrict__ w5, const float* __restrict__ w7,
                        u16* __restrict__ ws) {
    __shared__ u16 slab[32 * 270];
    int b = blockIdx.x, t = threadIdx.x;
    const float* src; u16* dst; int kmax, kt;
    if      (b <  2) { src = w1; dst = ws;          kmax = 54;  kt = b;      }
    else if (b <  4) { src = w3; dst = ws + 16384;  kmax = 54;  kt = b - 2;  }
    else if (b < 12) { src = w2; dst = ws + 32768;  kmax = 256; kt = b - 4;  }
    else if (b < 20) { src = w4; dst = ws + 98304;  kmax = 256; kt = b - 12; }
    else if (b < 28) { src = w5; dst = ws + 163840; kmax = 256; kt = b - 20; }
    else             { src = w7; dst = ws + 229376; kmax = 256; kt = b - 28; }

    #pragma unroll
    for (int it = 0; it < 8; ++it) {
        int flat = it * 1024 + t * 4;
        int row = flat >> 8, col = flat & 255;
        int k = kt * 32 + row;
        float4 v = make_float4(0.f, 0.f, 0.f, 0.f);
        if (k < kmax) v = *(const float4*)(src + k * 256 + col);
        u32* sp = (u32*)&slab[row * 270 + col];
        sp[0] = pk2(v.x, v.y);
        sp[1] = pk2(v.z, v.w);
    }
    __syncthreads();

    int lane = t & 63, wave = t >> 6, lr = lane & 15, kg = lane >> 4;
    #pragma unroll
    for (int i = 0; i < 4; ++i) {
        int ct = wave * 4 + i;
        u16 v[8];
        #pragma unroll
        for (int j = 0; j < 8; ++j)
            v[j] = slab[(kg * 8 + j) * 270 + ct * 16 + lr];
        uint4 o;
        o.x = (u32)v[0] | ((u32)v[1] << 16);
        o.y = (u32)v[2] | ((u32)v[3] << 16);
        o.z = (u32)v[4] | ((u32)v[5] << 16);
        o.w = (u32)v[6] | ((u32)v[7] << 16);
        *(uint4*)(dst + (size_t)(((kt * 16 + ct) * 64 + lane) * 8)) = o;
    }
}

// ---------------------------------------------------------------------------
// Fused critic (R21 structure, steady ~102.3 us). 512 thr / 8 waves,
// wr = batch-half / rho net, wc = column-tile. unroll 1 weight loops,
// S1 early-evict to SB, fused final dot, single-body-per-wave gather.
//
// THIS round: TWO-STAGE GATHER. Stage 1: all 512 threads coalesce-load
// obs/ag/g/act into an LDS raw area (f2b in flight; anchor staged as raw
// f32 so the sel comparison stays exact). Stage 2: the 2-part builders
// construct rows from LDS (u16 copies, ~5cyc issue) instead of scattered
// global loads (~200-900cyc latency in a ~30-deep serial chain). Also
// dedups the 3x re-read of obs body segments.
//
// LDS layout (u16), activation rows XOR-swizzled:
//   physical = row*stride + (logical_col ^ ((row&7)<<3))
//   inp: rows 0..95, stride 64  ([0, 6144))   (dead by rho -> f32 scratch)
//   h  : rows 0..95, stride 256 ([6144, 6144+24576)); S2 -> rows 32..63
//        raw staging lives in h rows 0..12 during gather (dead then)
//   SB : rows 0..31, stride 256 ([30720, 38912))  <- S1 early-evict region
// Total 77824 B -> 2 blocks/CU, 4 waves/SIMD.
// ---------------------------------------------------------------------------
#define H_OFF 6144
#define S2O   (32 * 256)
#define SBO   (H_OFF + 96 * 256)

__global__ __launch_bounds__(512) __attribute__((amdgpu_waves_per_eu(4, 4)))
void critic_kernel(
    const float* __restrict__ obs, const float* __restrict__ ag,
    const float* __restrict__ g,   const float* __restrict__ anchor,
    const float* __restrict__ act,
    const float* __restrict__ b1,  const float* __restrict__ b2,
    const float* __restrict__ b3,  const float* __restrict__ b4,
    const float* __restrict__ b5,  const float* __restrict__ b7,
    const float* __restrict__ w6,  const float* __restrict__ b6,
    const float* __restrict__ w8,  const float* __restrict__ b8,
    const u16* __restrict__ wsz, float* __restrict__ out, int B) {

    __shared__ u16 pool[SBO + 32 * 256];   // 38912 u16 = 77824 B

    const int t    = threadIdx.x;
    const int lane = t & 63;
    const int wave = t >> 6;     // 0..7
    const int wr   = wave >> 2;  // 0,1 : batch-lane half / rho net
    const int wc   = wave & 3;   // 0..3: 4 column-tiles
    const int lr   = lane & 15;
    const int lg   = lane >> 4;
    const int wg   = blockIdx.x;
    const int swr  = (lr & 7) << 3;   // row-XOR swizzle (h/inp rows are ..*16+lr)

    // ---- Gather stage 1: coalesced global -> LDS raw (all 512 threads).
    // Raw bf16 at pool[H_OFF + b*80 + off]: obs 0..54, ag 55..63, g 64..72,
    // act 73..76 (stride 80). Raw f32 anchor at pool[H_OFF+2560]: [32][9].
    {
        u16* raw = &pool[H_OFF];
        float* araw = (float*)&pool[H_OFF + 2560];
        const float* obsg = obs + (size_t)wg * 32 * 55;
        for (int i = t; i < 1760; i += 512) {
            int b = i / 55, c = i - b * 55;
            raw[b * 80 + c] = f2b(obsg[i]);
        }
        if (t < 288) {
            int b = t / 9, c = t - b * 9;
            size_t gi = (size_t)(wg * 32) * 9 + t;
            raw[b * 80 + 55 + c] = f2b(ag[gi]);
            raw[b * 80 + 64 + c] = f2b(g[gi]);
            araw[t] = anchor[gi];
        } else if (t < 416) {
            int ii = t - 288;               // 0..127 : act
            int b = ii >> 2, c = ii & 3;
            raw[b * 80 + 73 + c] = f2b(act[(size_t)(wg * 32) * 4 + ii]);
        }
    }
    __syncthreads();

    // ---- Gather stage 2: build pair rows from LDS raw (no global latency).
    // part0 on t in [0,96) (waves 0,1); part1 on t in [256,352) (waves 4,5):
    // every wave executes at most one branch body.
    {
        const int O1[3] = {0, 0, 1}, O2[3] = {1, 2, 2};
        const int JA[3] = {3, 4, 6}, KA[3] = {5, 7, 8};
        int part = -1, rr = 0;
        if (t < 96)                   { part = 0; rr = t; }
        else if (t >= 256 && t < 352) { part = 1; rr = t - 256; }
        if (part >= 0) {
            int p = rr >> 5, bl = rr & 31;
            const u16* rb = &pool[H_OFF + bl * 80];
            const float* araw = (const float*)&pool[H_OFF + 2560];
            int j = JA[p], k = KA[p];
            bool sel = (araw[bl * 9 + j] - araw[bl * 9 + k]) >= 0.0f;
            u16* row = &pool[rr * 64];
            const int sw = (rr & 7) << 3;
            const u16 ONE = 0x3F80;
            if (part == 0) {
                int bit2 = sel ? j : k;
                int oi = sel ? O1[p] : O2[p];
                row[0 ^ sw] = rb[55 + p];
                row[1 ^ sw] = rb[55 + bit2];
                row[2 ^ sw] = rb[64 + p];
                row[3 ^ sw] = rb[64 + bit2];
                for (int c = 0; c < 10; ++c) row[(4 + c) ^ sw] = rb[c];
                row[14 ^ sw] = (oi == 0) ? ONE : 0;
                row[15 ^ sw] = (oi == 1) ? ONE : 0;
                row[16 ^ sw] = (oi == 2) ? ONE : 0;
                for (int c = 0; c < 15; ++c) row[(17 + c) ^ sw] = rb[10 + 15 * oi + c];
            } else {
                int oj = sel ? O2[p] : O1[p];
                row[32 ^ sw] = (oj == 0) ? ONE : 0;
                row[33 ^ sw] = (oj == 1) ? ONE : 0;
                row[34 ^ sw] = (oj == 2) ? ONE : 0;
                for (int c = 0; c < 15; ++c) row[(35 + c) ^ sw] = rb[10 + 15 * oj + c];
                for (int c = 0; c < 4; ++c)  row[(50 + c) ^ sw] = rb[73 + c];
                for (int c = 54; c < 64; ++c) row[c ^ sw] = 0;
            }
        }
    }
    __syncthreads();

    u32 s2w[4][2];    // net1 pair-sums (brief: epilogue -> post-barrier write)

    // ---- Phi networks (net 0: w1/w2, net 1: w3/w4) ----
    for (int net = 0; net < 2; ++net) {
        const u16* Wl1 = wsz + (net ? 16384 : 0);
        const u16* Wl2 = wsz + 32768 + (net ? 65536 : 0);
        const float* bl1 = net ? b3 : b1;
        const float* bl2 = net ? b4 : b2;

        // Layer 1: A=W1^T frags, B=inp rows rt=2p+wr. D=(batch=lr, hid=lg*4+reg)
        f4 acc[3][4];
        #pragma unroll
        for (int p = 0; p < 3; ++p)
            #pragma unroll
            for (int c = 0; c < 4; ++c) acc[p][c] = (f4){0.f, 0.f, 0.f, 0.f};
        __builtin_amdgcn_s_setprio(1);
        #pragma unroll 1
        for (int kt = 0; kt < 2; ++kt) {
            bf8 wfr[4];
            #pragma unroll
            for (int c = 0; c < 4; ++c)
                wfr[c] = *(const bf8*)(Wl1 + (size_t)(((kt * 16 + wc * 4 + c) * 64 + lane) * 8));
            #pragma unroll
            for (int p = 0; p < 3; ++p) {
                bf8 xfr = *(const bf8*)(&pool[((2 * p + wr) * 16 + lr) * 64 + ((kt * 32 + lg * 8) ^ swr)]);
                #pragma unroll
                for (int c = 0; c < 4; ++c)
                    acc[p][c] = __builtin_amdgcn_mfma_f32_16x16x32_bf16(wfr[c], xfr, acc[p][c], 0, 0, 0);
            }
        }
        __builtin_amdgcn_s_setprio(0);
        #pragma unroll
        for (int c = 0; c < 4; ++c) {
            float4 bv = *(const float4*)(bl1 + (wc * 4 + c) * 16 + lg * 4);
            #pragma unroll
            for (int p = 0; p < 3; ++p) {
                uint2 w;
                w.x = pk2(fmaxf(acc[p][c][0] + bv.x, 0.f), fmaxf(acc[p][c][1] + bv.y, 0.f));
                w.y = pk2(fmaxf(acc[p][c][2] + bv.z, 0.f), fmaxf(acc[p][c][3] + bv.w, 0.f));
                *(uint2*)&pool[H_OFF + ((2 * p + wr) * 16 + lr) * 256 + ((((wc * 4 + c) * 16) + lg * 4) ^ swr)] = w;
            }
        }
        __syncthreads();

        // Layer 2: A=W2^T frags, B=h rows rt=2p+wr. Relu + in-register pair-sum.
        f4 acc2[3][4];
        #pragma unroll
        for (int p = 0; p < 3; ++p)
            #pragma unroll
            for (int c = 0; c < 4; ++c) acc2[p][c] = (f4){0.f, 0.f, 0.f, 0.f};
        __builtin_amdgcn_s_setprio(1);
        #pragma unroll 1
        for (int ks = 0; ks < 8; ++ks) {
            bf8 wfr[4];
            #pragma unroll
            for (int c = 0; c < 4; ++c)
                wfr[c] = *(const bf8*)(Wl2 + (size_t)(((ks * 16 + wc * 4 + c) * 64 + lane) * 8));
            #pragma unroll
            for (int p = 0; p < 3; ++p) {
                bf8 hfr = *(const bf8*)(&pool[H_OFF + ((2 * p + wr) * 16 + lr) * 256 + ((ks * 32 + lg * 8) ^ swr)]);
                #pragma unroll
                for (int c = 0; c < 4; ++c)
                    acc2[p][c] = __builtin_amdgcn_mfma_f32_16x16x32_bf16(wfr[c], hfr, acc2[p][c], 0, 0, 0);
            }
        }
        __builtin_amdgcn_s_setprio(0);
        #pragma unroll
        for (int c = 0; c < 4; ++c) {
            float4 bv = *(const float4*)(bl2 + (wc * 4 + c) * 16 + lg * 4);
            f4 sv = (f4){0.f, 0.f, 0.f, 0.f};
            #pragma unroll
            for (int p = 0; p < 3; ++p) {
                sv[0] += fmaxf(acc2[p][c][0] + bv.x, 0.f);
                sv[1] += fmaxf(acc2[p][c][1] + bv.y, 0.f);
                sv[2] += fmaxf(acc2[p][c][2] + bv.z, 0.f);
                sv[3] += fmaxf(acc2[p][c][3] + bv.w, 0.f);
            }
            if (net == 0) {
                // S1 early-evict: write straight to the dedicated SB region
                // (disjoint from h -> no race with other waves' h reads).
                uint2 w;
                w.x = pk2(sv[0], sv[1]);
                w.y = pk2(sv[2], sv[3]);
                *(uint2*)&pool[SBO + (wr * 16 + lr) * 256 + ((((wc * 4 + c) * 16) + lg * 4) ^ swr)] = w;
            } else {
                s2w[c][0] = pk2(sv[0], sv[1]);
                s2w[c][1] = pk2(sv[2], sv[3]);
            }
        }
        __syncthreads();  // h reads done before next net overwrites h / S2 write
    }

    // ---- Write S2 into dead h rows 32..63 (all h reads completed) ----
    #pragma unroll
    for (int c = 0; c < 4; ++c) {
        int base = H_OFF + S2O + (wr * 16 + lr) * 256 + ((((wc * 4 + c) * 16) + lg * 4) ^ swr);
        *(uint2*)&pool[base] = *(uint2*)&s2w[c][0];
    }
    __syncthreads();

    // ---- Rho hidden layer + FUSED final dot ----
    // wr picks the net (wr=0: S1@SB/W5/b5/w6, wr=1: S2/W7/b7/w8).
    {
        const u16* Wr    = wsz + (wr ? 229376 : 163840);
        const int sbase  = wr ? (H_OFF + S2O) : SBO;
        const float* br  = wr ? b7 : b5;
        const float* wq  = wr ? w8 : w6;
        f4 racc[2][4];
        #pragma unroll
        for (int rt = 0; rt < 2; ++rt)
            #pragma unroll
            for (int c = 0; c < 4; ++c) racc[rt][c] = (f4){0.f, 0.f, 0.f, 0.f};
        __builtin_amdgcn_s_setprio(1);
        #pragma unroll 1
        for (int ks = 0; ks < 8; ++ks) {
            bf8 wf[4];
            #pragma unroll
            for (int c = 0; c < 4; ++c)
                wf[c] = *(const bf8*)(Wr + (size_t)(((ks * 16 + wc * 4 + c) * 64 + lane) * 8));
            #pragma unroll
            for (int rt = 0; rt < 2; ++rt) {
                bf8 sf = *(const bf8*)(&pool[sbase + (rt * 16 + lr) * 256 + ((ks * 32 + lg * 8) ^ swr)]);
                #pragma unroll
                for (int c = 0; c < 4; ++c)
                    racc[rt][c] = __builtin_amdgcn_mfma_f32_16x16x32_bf16(wf[c], sf, racc[rt][c], 0, 0, 0);
            }
        }
        __builtin_amdgcn_s_setprio(0);
        // Fused epilogue: q-partial = sum_h relu(racc + b) * wq[h], f32.
        // Lane holds hidden units (wc*4+c)*16+lg*4+i for batch rt*16+lr.
        float part[2] = {0.f, 0.f};
        #pragma unroll
        for (int c = 0; c < 4; ++c) {
            float4 bv = *(const float4*)(br + (wc * 4 + c) * 16 + lg * 4);
            float4 wv = *(const float4*)(wq + (wc * 4 + c) * 16 + lg * 4);
            #pragma unroll
            for (int rt = 0; rt < 2; ++rt) {
                part[rt] += fmaxf(racc[rt][c][0] + bv.x, 0.f) * wv.x
                          + fmaxf(racc[rt][c][1] + bv.y, 0.f) * wv.y
                          + fmaxf(racc[rt][c][2] + bv.z, 0.f) * wv.z
                          + fmaxf(racc[rt][c][3] + bv.w, 0.f) * wv.w;
            }
        }
        // Reduce over the 4 lg quads (lane bits 4,5); all lanes same-lr equal.
        #pragma unroll
        for (int rt = 0; rt < 2; ++rt) {
            part[rt] += __shfl_xor(part[rt], 16);
            part[rt] += __shfl_xor(part[rt], 32);
        }
        // One f32 partial per (net, batch, wc) into the dead inp region.
        if (lane < 16) {
            float* fs = (float*)pool;
            fs[(wr * 32 + lane) * 4 + wc]      = part[0];
            fs[(wr * 32 + 16 + lane) * 4 + wc] = part[1];
        }
        __syncthreads();
    }

    // ---- Final reduce: 64 threads sum the 4 wc partials. FP32 OUT ----
    if (t < 64) {
        int net = t >> 5, b = t & 31;
        const float* fs = (const float*)pool;
        float qv = net ? b8[0] : b6[0];
        #pragma unroll
        for (int p = 0; p < 4; ++p)
            qv += fs[(net * 32 + b) * 4 + p];
        out[net * B + wg * 32 + b] = qv;
    }
}

extern "C" void kernel_launch(void* const* d_in, const int* in_sizes, int n_in,
                              void* d_out, int out_size, void* d_ws, size_t ws_size,
                              hipStream_t stream) {
    const float* obs = (const float*)d_in[0];
    const float* ag  = (const float*)d_in[1];
    const float* g   = (const float*)d_in[2];
    const float* anc = (const float*)d_in[3];
    const float* act = (const float*)d_in[4];
    const float* w1  = (const float*)d_in[5];
    const float* b1  = (const float*)d_in[6];
    const float* w2  = (const float*)d_in[7];
    const float* b2  = (const float*)d_in[8];
    const float* w3  = (const float*)d_in[9];
    const float* b3  = (const float*)d_in[10];
    const float* w4  = (const float*)d_in[11];
    const float* b4  = (const float*)d_in[12];
    const float* w5  = (const float*)d_in[13];
    const float* b5  = (const float*)d_in[14];
    const float* w6  = (const float*)d_in[15];
    const float* b6  = (const float*)d_in[16];
    const float* w7  = (const float*)d_in[17];
    const float* b7  = (const float*)d_in[18];
    const float* w8  = (const float*)d_in[19];
    const float* b8  = (const float*)d_in[20];
    u16* ws    = (u16*)d_ws;
    float* out = (float*)d_out;
    int B = in_sizes[0] / 55;

    swz_all<<<36, 256, 0, stream>>>(w1, w3, w2, w4, w5, w7, ws);
    critic_kernel<<<(B + 31) / 32, 512, 0, stream>>>(obs, ag, g, anc, act,
                                                     b1, b2, b3, b4, b5, b7,
                                                     w6, b6, w8, b8, ws, out, B);
}